// Round 2
// baseline (737.651 us; speedup 1.0000x reference)
//
#include <hip/hip_runtime.h>

#define T_SEQ 2048
#define D_MODEL 4096
#define NH 32
#define NG 8
#define HD 128

typedef unsigned short u16;
typedef __bf16 bf16x8 __attribute__((ext_vector_type(8)));
typedef float f32x4 __attribute__((ext_vector_type(4)));

#define AS1 __attribute__((address_space(1)))
#define AS3 __attribute__((address_space(3)))

__device__ __forceinline__ void async_cp16(const u16* g, u16* l) {
  // global -> LDS direct copy, 16B per lane. LDS dest is wave-uniform base + lane*16.
  __builtin_amdgcn_global_load_lds((AS1 void*)g, (AS3 void*)l, 16, 0, 0);
}

__device__ __forceinline__ u16 f2bf(float f){
  union { float f; unsigned x; } v; v.f = f;
  unsigned r = v.x + 0x7FFFu + ((v.x >> 16) & 1u);
  return (u16)(r >> 16);
}
__device__ __forceinline__ u16 to_bf(float f){ return f2bf(f); }
__device__ __forceinline__ u16 to_bf(u16 u){ return u; }

// ---------------- convert fp32 -> bf16, vectorized ----------------
__global__ __launch_bounds__(256) void cvt_k(const float* __restrict__ in,
                                             u16* __restrict__ out, int n4)
{
  int i = blockIdx.x * 256 + threadIdx.x;
  if (i >= n4) return;
  float4 v = *(const float4*)&in[(size_t)i * 4];
  short4 o;
  o.x = (short)f2bf(v.x); o.y = (short)f2bf(v.y);
  o.z = (short)f2bf(v.z); o.w = (short)f2bf(v.w);
  *(short4*)&out[(size_t)i * 4] = o;
}

// ---------------- transpose + optional cvt: out[c][r] = bf16(in[r][c]) ----------------
template<typename TIN>
__global__ __launch_bounds__(256) void transpose_k(const TIN* __restrict__ in,
                                                   u16* __restrict__ out, int R, int C)
{
  int z = blockIdx.z;
  in  += (size_t)z * R * C;
  out += (size_t)z * R * C;
  __shared__ __align__(16) u16 tile[32][36];
  int c0 = blockIdx.x * 32, r0 = blockIdx.y * 32;
  int t = threadIdx.x;
  int lr = t >> 3, lc = (t & 7) * 4;
  const TIN* src = &in[(size_t)(r0 + lr) * C + c0 + lc];
  #pragma unroll
  for (int i = 0; i < 4; i++) tile[lr][lc + i] = to_bf(src[i]);
  __syncthreads();
  short4 v;
  v.x = (short)tile[lc + 0][lr];
  v.y = (short)tile[lc + 1][lr];
  v.z = (short)tile[lc + 2][lr];
  v.w = (short)tile[lc + 3][lr];
  *(short4*)&out[(size_t)(c0 + lr) * R + r0 + lc] = v;
}

// ---------------- GEMM: C[M x N] = A[M x K] * BT[N x K]^T, bf16 in, fp32 acc ------
// LDS tiles [128 rows][64 k] unpadded, 16B-group XOR swizzle: phys_g = g ^ (row&7).
// MODE 0: store bf16 to Cout
// MODE 1: KV scatter: col -> (g,s,hd) into Kout/Vout[g][t][hd] (bf16)
// MODE 2: store fp32 to Fout with fp32 bias add
template<int MODE>
__global__ __launch_bounds__(256) void gemm_k(
    const u16* __restrict__ A, const u16* __restrict__ BT,
    u16* __restrict__ Cout, u16* __restrict__ Kout, u16* __restrict__ Vout,
    float* __restrict__ Fout, const float* __restrict__ bias, int K, int N)
{
  __shared__ __align__(16) u16 sA[128 * 64];
  __shared__ __align__(16) u16 sB[128 * 64];
  const int t = threadIdx.x;
  const int lane = t & 63, wave = t >> 6;
  const int quad = lane >> 4, lm = lane & 15;
  const int wm = wave >> 1, wn = wave & 1;
  const int m0 = blockIdx.y * 128, n0 = blockIdx.x * 128;
  const f32x4 fzero = {0.f, 0.f, 0.f, 0.f};

  const int sr_sub = lane >> 3;            // 0..7
  const int sgl = (lane & 7) ^ sr_sub;     // swizzled logical 16B group

  f32x4 acc[4][4];
  #pragma unroll
  for (int i = 0; i < 4; i++)
    #pragma unroll
    for (int j = 0; j < 4; j++) acc[i][j] = fzero;

  for (int k0 = 0; k0 < K; k0 += 64) {
    #pragma unroll
    for (int c = 0; c < 4; c++) {
      int r = c * 32 + wave * 8 + sr_sub;
      async_cp16(&A [(size_t)(m0 + r) * K + k0 + sgl * 8], &sA[(c * 256 + wave * 64) * 8]);
      async_cp16(&BT[(size_t)(n0 + r) * K + k0 + sgl * 8], &sB[(c * 256 + wave * 64) * 8]);
    }
    __syncthreads();
    #pragma unroll
    for (int kb = 0; kb < 2; kb++) {
      bf16x8 af[4], bfr[4];
      #pragma unroll
      for (int mt = 0; mt < 4; mt++) {
        int row = wm * 64 + mt * 16 + lm;
        af[mt] = *(const bf16x8*)&sA[row * 64 + (((kb * 4 + quad) ^ (lm & 7)) * 8)];
      }
      #pragma unroll
      for (int nt = 0; nt < 4; nt++) {
        int row = wn * 64 + nt * 16 + lm;
        bfr[nt] = *(const bf16x8*)&sB[row * 64 + (((kb * 4 + quad) ^ (lm & 7)) * 8)];
      }
      #pragma unroll
      for (int mt = 0; mt < 4; mt++)
        #pragma unroll
        for (int nt = 0; nt < 4; nt++)
          acc[mt][nt] = __builtin_amdgcn_mfma_f32_16x16x32_bf16(af[mt], bfr[nt], acc[mt][nt], 0, 0, 0);
    }
    __syncthreads();
  }

  #pragma unroll
  for (int mt = 0; mt < 4; mt++) {
    #pragma unroll
    for (int nt = 0; nt < 4; nt++) {
      #pragma unroll
      for (int r = 0; r < 4; r++) {
        int grow = m0 + wm * 64 + mt * 16 + quad * 4 + r;
        int gcol = n0 + wn * 64 + nt * 16 + lm;
        float v = acc[mt][nt][r];
        if (MODE == 0) {
          Cout[(size_t)grow * N + gcol] = f2bf(v);
        } else if (MODE == 1) {
          int g = gcol >> 8, s = (gcol >> 7) & 1, hd = gcol & 127;
          u16* dst = s ? Vout : Kout;
          dst[((size_t)g * T_SEQ + grow) * HD + hd] = f2bf(v);
        } else {
          Fout[(size_t)grow * N + gcol] = v + bias[gcol];
        }
      }
    }
  }
}

// ---------------- flash attention (no K/V staging): Q[t][h*128], K[g][t][128],
// Vt[g][128][t] -> ctx[t][h*128]
// K/V per group = 1 MB total -> L2-resident; read MFMA fragments DIRECTLY from
// global (16B/lane), no LDS staging, no __syncthreads in the kv loop.  LDS holds
// only the wave-private P buffer (9 KB) -> occupancy is VGPR-limited, not LDS.
// XCD remap: dispatch id % 8 = KV group, so each XCD's L2 caches exactly one
// group's K+V; longest q-blocks first within each XCD slice.
// Fixed-shift softmax: p = exp2(s*C1 + C2) never overflows; ratio shift-invariant.
__global__ __launch_bounds__(256, 3) void attn_k(
    const u16* __restrict__ Q, const u16* __restrict__ Kb,
    const u16* __restrict__ Vt, u16* __restrict__ ctx)
{
  __shared__ __align__(16) u16 sP[4 * 16 * 72];  // per-wave [16 q][64 kv + pad8]
  const int t = threadIdx.x;
  const int lane = t & 63, wave = t >> 6;
  const int quad = lane >> 4, lm = lane & 15;

  // id -> (g, rep, q-block): round-robin %8 pins group g to one XCD
  const int id = blockIdx.x + gridDim.x * blockIdx.y;
  const int g = id & 7;
  const int idx = id >> 3;                       // 0..127
  const int h = g * 4 + (idx & 3);               // REP = 4
  const int q0 = (31 - (idx >> 2)) * 64;         // longest first

  const float scale = 0.088388347648318447f;     // 1/sqrt(128)
  const float C1 = scale * 1.4426950408889634f;  // to exp2 domain
  const float C2 = -14.0f * 1.4426950408889634f; // fixed shift M0 = 14
  const f32x4 fzero = {0.f, 0.f, 0.f, 0.f};

  bf16x8 aq[4];
  {
    const u16* qp = Q + (size_t)(q0 + wave * 16 + lm) * D_MODEL + h * HD + quad * 8;
    #pragma unroll
    for (int kb = 0; kb < 4; kb++) aq[kb] = *(const bf16x8*)(qp + kb * 32);
  }
  f32x4 o[8];
  #pragma unroll
  for (int i = 0; i < 8; i++) o[i] = fzero;
  float l4[4];
  #pragma unroll
  for (int r = 0; r < 4; r++) l4[r] = 0.f;

  const u16* Kg = Kb + (size_t)g * T_SEQ * HD;
  const u16* Vg = Vt + (size_t)g * HD * T_SEQ;
  u16* sPw = sP + wave * 16 * 72;

  for (int kv0 = 0; kv0 < q0 + 64; kv0 += 64) {
    // S = Q Ktile^T : B-fragment rows = kv (nt*16+lm), k-offset (kb*4+quad)*8,
    // read directly from K[g][kv][hd] (row stride 256B, 16B/lane, L2-resident)
    f32x4 s[4];
    #pragma unroll
    for (int nt = 0; nt < 4; nt++) {
      s[nt] = fzero;
      const u16* kp = Kg + (size_t)(kv0 + nt * 16 + lm) * HD + quad * 8;
      #pragma unroll
      for (int kb = 0; kb < 4; kb++) {
        bf16x8 bk = *(const bf16x8*)(kp + kb * 32);
        s[nt] = __builtin_amdgcn_mfma_f32_16x16x32_bf16(aq[kb], bk, s[nt], 0, 0, 0);
      }
    }

    // fixed-shift softmax numerator; per-lane partial l; no cross-lane ops
    #pragma unroll
    for (int r = 0; r < 4; r++) {
      int qr = q0 + wave * 16 + quad * 4 + r;
      #pragma unroll
      for (int nt = 0; nt < 4; nt++) {
        int kvc = kv0 + nt * 16 + lm;
        float p = exp2f(fmaf(s[nt][r], C1, C2));
        p = (kvc > qr) ? 0.f : p;
        l4[r] += p;
        sPw[(quad * 4 + r) * 72 + nt * 16 + lm] = f2bf(p);
      }
    }
    // no barrier: sPw is wave-private; lgkmcnt orders ds_write -> ds_read.

    // O += P * Vtile : B-fragment rows = d (n8*16+lm), k-offset (kb2*4+quad)*8,
    // read directly from V^T[g][hd][t] (row stride 4KB, 16B/lane, L2-resident)
    #pragma unroll
    for (int kb2 = 0; kb2 < 2; kb2++) {
      bf16x8 ap = *(const bf16x8*)&sPw[lm * 72 + kb2 * 32 + quad * 8];
      const u16* vp = Vg + (size_t)lm * T_SEQ + kv0 + kb2 * 32 + quad * 8;
      #pragma unroll
      for (int n8 = 0; n8 < 8; n8++) {
        bf16x8 bv = *(const bf16x8*)(vp + (size_t)(n8 * 16) * T_SEQ);
        o[n8] = __builtin_amdgcn_mfma_f32_16x16x32_bf16(ap, bv, o[n8], 0, 0, 0);
      }
    }
  }

  // one-time l reduction across the 16 lm-lanes (xor offsets stay in-quad)
  #pragma unroll
  for (int r = 0; r < 4; r++) {
    #pragma unroll
    for (int off = 1; off < 16; off <<= 1) l4[r] += __shfl_xor(l4[r], off, 64);
  }

  #pragma unroll
  for (int r = 0; r < 4; r++) {
    float inv = 1.f / l4[r];
    #pragma unroll
    for (int n8 = 0; n8 < 8; n8++) {
      ctx[(size_t)(q0 + wave * 16 + quad * 4 + r) * D_MODEL + h * HD + n8 * 16 + lm]
          = f2bf(o[n8][r] * inv);
    }
  }
}

extern "C" void kernel_launch(void* const* d_in, const int* in_sizes, int n_in,
                              void* d_out, int out_size, void* d_ws, size_t ws_size,
                              hipStream_t stream)
{
  const float* x   = (const float*)d_in[0];
  const float* Wq  = (const float*)d_in[1];
  const float* Wkv = (const float*)d_in[2];
  const float* Wo  = (const float*)d_in[3];
  const float* bo  = (const float*)d_in[4];
  float* out = (float*)d_out;

  char* ws = (char*)d_ws;
  const size_t SZ_T   = 33554432;  // 4096*4096*2 (bf16)
  const size_t SZ_ACT = 16777216;  // 2048*4096*2 (bf16)
  const size_t SZ_KV  = 4194304;   // 8*2048*128*2 (bf16)
  u16* Tb = (u16*)(ws);
  u16* Xb = (u16*)(ws + SZ_T);
  u16* Qb = (u16*)(ws + SZ_T + SZ_ACT);
  u16* Cx = (u16*)(ws + SZ_T + 2 * SZ_ACT);
  u16* Kb = (u16*)(ws + SZ_T + 3 * SZ_ACT);
  u16* Vb = (u16*)(ws + SZ_T + 3 * SZ_ACT + SZ_KV);
  u16* Vt = (u16*)(ws + SZ_T + 3 * SZ_ACT + 2 * SZ_KV);

  // 0. x -> bf16
  cvt_k<<<dim3(8192, 1, 1), 256, 0, stream>>>(x, Xb, 2097152);
  // 1. Q = x @ Wq           (Wq^T staged into Tb, fp32->bf16)
  transpose_k<float><<<dim3(128, 128, 1), 256, 0, stream>>>(Wq, Tb, 4096, 4096);
  gemm_k<0><<<dim3(32, 16, 1), 256, 0, stream>>>(Xb, Tb, Qb, nullptr, nullptr, nullptr, nullptr, 4096, 4096);
  // 2. K,V = split(x @ Wkv)
  transpose_k<float><<<dim3(64, 128, 1), 256, 0, stream>>>(Wkv, Tb, 4096, 2048);
  gemm_k<1><<<dim3(16, 16, 1), 256, 0, stream>>>(Xb, Tb, nullptr, Kb, Vb, nullptr, nullptr, 4096, 2048);
  // 3. V^T per group: [g][t][hd] -> [g][hd][t]  (bf16 -> bf16)
  transpose_k<u16><<<dim3(4, 64, 8), 256, 0, stream>>>(Vb, Vt, 2048, 128);
  // 4. flash attention -> ctx (bf16)
  attn_k<<<dim3(32, 32, 1), 256, 0, stream>>>(Qb, Kb, Vt, Cx);
  // 5. out = ctx @ Wo + bo  (fp32 out, fp32 bias)
  transpose_k<float><<<dim3(128, 128, 1), 256, 0, stream>>>(Wo, Tb, 4096, 4096);
  gemm_k<2><<<dim3(32, 16, 1), 256, 0, stream>>>(Cx, Tb, nullptr, nullptr, nullptr, out, bo, 4096, 4096);
}

// Round 3
// 516.220 us; speedup vs baseline: 1.4289x; 1.4289x over previous
//
#include <hip/hip_runtime.h>

#define T_SEQ 2048
#define D_MODEL 4096
#define NH 32
#define NG 8
#define HD 128

typedef unsigned short u16;
typedef __bf16 bf16x8 __attribute__((ext_vector_type(8)));
typedef float f32x4 __attribute__((ext_vector_type(4)));

#define AS1 __attribute__((address_space(1)))
#define AS3 __attribute__((address_space(3)))

__device__ __forceinline__ void async_cp16(const u16* g, u16* l) {
  // global -> LDS direct copy, 16B per lane. LDS dest is wave-uniform base + lane*16.
  __builtin_amdgcn_global_load_lds((AS1 void*)g, (AS3 void*)l, 16, 0, 0);
}

__device__ __forceinline__ u16 f2bf(float f){
  union { float f; unsigned x; } v; v.f = f;
  unsigned r = v.x + 0x7FFFu + ((v.x >> 16) & 1u);
  return (u16)(r >> 16);
}
__device__ __forceinline__ u16 to_bf(float f){ return f2bf(f); }
__device__ __forceinline__ u16 to_bf(u16 u){ return u; }

// ---------------- convert fp32 -> bf16, vectorized ----------------
__global__ __launch_bounds__(256) void cvt_k(const float* __restrict__ in,
                                             u16* __restrict__ out, int n4)
{
  int i = blockIdx.x * 256 + threadIdx.x;
  if (i >= n4) return;
  float4 v = *(const float4*)&in[(size_t)i * 4];
  short4 o;
  o.x = (short)f2bf(v.x); o.y = (short)f2bf(v.y);
  o.z = (short)f2bf(v.z); o.w = (short)f2bf(v.w);
  *(short4*)&out[(size_t)i * 4] = o;
}

// ---------------- transpose + optional cvt: out[c][r] = bf16(in[r][c]) ----------------
template<typename TIN>
__global__ __launch_bounds__(256) void transpose_k(const TIN* __restrict__ in,
                                                   u16* __restrict__ out, int R, int C)
{
  int z = blockIdx.z;
  in  += (size_t)z * R * C;
  out += (size_t)z * R * C;
  __shared__ __align__(16) u16 tile[32][36];
  int c0 = blockIdx.x * 32, r0 = blockIdx.y * 32;
  int t = threadIdx.x;
  int lr = t >> 3, lc = (t & 7) * 4;
  const TIN* src = &in[(size_t)(r0 + lr) * C + c0 + lc];
  #pragma unroll
  for (int i = 0; i < 4; i++) tile[lr][lc + i] = to_bf(src[i]);
  __syncthreads();
  short4 v;
  v.x = (short)tile[lc + 0][lr];
  v.y = (short)tile[lc + 1][lr];
  v.z = (short)tile[lc + 2][lr];
  v.w = (short)tile[lc + 3][lr];
  *(short4*)&out[(size_t)(c0 + lr) * R + r0 + lc] = v;
}

// ---------------- GEMM: C[M x N] = A[M x K] * BT[N x K]^T, bf16 in, fp32 acc ------
// LDS tiles [128 rows][64 k] unpadded, 16B-group XOR swizzle: phys_g = g ^ (row&7).
// MODE 0: store bf16 to Cout
// MODE 1: KV scatter: col -> (g,s,hd) into Kout/Vout[g][t][hd] (bf16)
// MODE 2: store fp32 to Fout with fp32 bias add
template<int MODE>
__global__ __launch_bounds__(256) void gemm_k(
    const u16* __restrict__ A, const u16* __restrict__ BT,
    u16* __restrict__ Cout, u16* __restrict__ Kout, u16* __restrict__ Vout,
    float* __restrict__ Fout, const float* __restrict__ bias, int K, int N)
{
  __shared__ __align__(16) u16 sA[128 * 64];
  __shared__ __align__(16) u16 sB[128 * 64];
  const int t = threadIdx.x;
  const int lane = t & 63, wave = t >> 6;
  const int quad = lane >> 4, lm = lane & 15;
  const int wm = wave >> 1, wn = wave & 1;
  const int m0 = blockIdx.y * 128, n0 = blockIdx.x * 128;
  const f32x4 fzero = {0.f, 0.f, 0.f, 0.f};

  const int sr_sub = lane >> 3;            // 0..7
  const int sgl = (lane & 7) ^ sr_sub;     // swizzled logical 16B group

  f32x4 acc[4][4];
  #pragma unroll
  for (int i = 0; i < 4; i++)
    #pragma unroll
    for (int j = 0; j < 4; j++) acc[i][j] = fzero;

  for (int k0 = 0; k0 < K; k0 += 64) {
    #pragma unroll
    for (int c = 0; c < 4; c++) {
      int r = c * 32 + wave * 8 + sr_sub;
      async_cp16(&A [(size_t)(m0 + r) * K + k0 + sgl * 8], &sA[(c * 256 + wave * 64) * 8]);
      async_cp16(&BT[(size_t)(n0 + r) * K + k0 + sgl * 8], &sB[(c * 256 + wave * 64) * 8]);
    }
    __syncthreads();
    #pragma unroll
    for (int kb = 0; kb < 2; kb++) {
      bf16x8 af[4], bfr[4];
      #pragma unroll
      for (int mt = 0; mt < 4; mt++) {
        int row = wm * 64 + mt * 16 + lm;
        af[mt] = *(const bf16x8*)&sA[row * 64 + (((kb * 4 + quad) ^ (lm & 7)) * 8)];
      }
      #pragma unroll
      for (int nt = 0; nt < 4; nt++) {
        int row = wn * 64 + nt * 16 + lm;
        bfr[nt] = *(const bf16x8*)&sB[row * 64 + (((kb * 4 + quad) ^ (lm & 7)) * 8)];
      }
      #pragma unroll
      for (int mt = 0; mt < 4; mt++)
        #pragma unroll
        for (int nt = 0; nt < 4; nt++)
          acc[mt][nt] = __builtin_amdgcn_mfma_f32_16x16x32_bf16(af[mt], bfr[nt], acc[mt][nt], 0, 0, 0);
    }
    __syncthreads();
  }

  #pragma unroll
  for (int mt = 0; mt < 4; mt++) {
    #pragma unroll
    for (int nt = 0; nt < 4; nt++) {
      #pragma unroll
      for (int r = 0; r < 4; r++) {
        int grow = m0 + wm * 64 + mt * 16 + quad * 4 + r;
        int gcol = n0 + wn * 64 + nt * 16 + lm;
        float v = acc[mt][nt][r];
        if (MODE == 0) {
          Cout[(size_t)grow * N + gcol] = f2bf(v);
        } else if (MODE == 1) {
          int g = gcol >> 8, s = (gcol >> 7) & 1, hd = gcol & 127;
          u16* dst = s ? Vout : Kout;
          dst[((size_t)g * T_SEQ + grow) * HD + hd] = f2bf(v);
        } else {
          Fout[(size_t)grow * N + gcol] = v + bias[gcol];
        }
      }
    }
  }
}

// ---------------- flash attention, double-buffered staging + counted vmcnt ------
// Q[t][h*128], K[g][t][128], Vt[g][128][t] -> ctx[t][h*128]
// sK/sV double-buffered (74.7 KB LDS, 2 blocks/CU); stage(t+2) issues after the
// retire barrier; loop top waits vmcnt(8) (= one tile's 8 gload_lds in flight,
// never 0 except the final tile) so staging latency hides under a full tile of
// QK+softmax+PV compute.  vmcnt FIFO: at iter t top, outstanding = stage(t)
// [maybe] + stage(t+1); draining to 8 completes stage(t) exactly.  Q's 4 reg
// loads only add to the drained prefix.  XCD remap: id%8 = KV group pins each
// group's 1MB K/V to one XCD's L2.  Fixed-shift softmax: p = exp2(s*C1+C2),
// shift-invariant ratio, no running max, l reduced once after the loop.
__global__ __launch_bounds__(256) void attn_k(
    const u16* __restrict__ Q, const u16* __restrict__ Kb,
    const u16* __restrict__ Vt, u16* __restrict__ ctx)
{
  __shared__ __align__(16) u16 sK[2 * 64 * 128];
  __shared__ __align__(16) u16 sV[2 * 128 * 64];
  __shared__ __align__(16) u16 sP[4 * 16 * 72];  // per-wave [16 q][64 kv + pad8]
  const int t = threadIdx.x;
  const int lane = t & 63, wave = t >> 6;
  const int quad = lane >> 4, lm = lane & 15;

  // id -> (g, rep, q-block): round-robin %8 pins group g to one XCD
  const int id = blockIdx.x + gridDim.x * blockIdx.y;
  const int g = id & 7;
  const int idx = id >> 3;                       // 0..127
  const int h = g * 4 + (idx & 3);               // REP = 4
  const int q0 = (31 - (idx >> 2)) * 64;         // longest first
  const int nt = (q0 >> 6) + 1;                  // causal kv-tile count

  const float scale = 0.088388347648318447f;     // 1/sqrt(128)
  const float C1 = scale * 1.4426950408889634f;  // to exp2 domain
  const float C2 = -14.0f * 1.4426950408889634f; // fixed shift M0 = 14
  const f32x4 fzero = {0.f, 0.f, 0.f, 0.f};

  bf16x8 aq[4];
  {
    const u16* qp = Q + (size_t)(q0 + wave * 16 + lm) * D_MODEL + h * HD + quad * 8;
    #pragma unroll
    for (int kb = 0; kb < 4; kb++) aq[kb] = *(const bf16x8*)(qp + kb * 32);
  }
  f32x4 o[8];
  #pragma unroll
  for (int i = 0; i < 8; i++) o[i] = fzero;
  float l4[4];
  #pragma unroll
  for (int r = 0; r < 4; r++) l4[r] = 0.f;

  const u16* Kg = Kb + (size_t)g * T_SEQ * HD;
  const u16* Vg = Vt + (size_t)g * HD * T_SEQ;
  u16* sPw = sP + wave * 16 * 72;

  // staging geometry (8 gload_lds per thread per tile: 4 K + 4 V)
  const int k_r_sub = lane >> 4;                    // 0..3 (16 groups/row for sK)
  const int v_r_sub = lane >> 3;                    // 0..7 (8 groups/row for sV)
  const int v_gl = (lane & 7) ^ v_r_sub;

  auto stage = [&](int td) {
    const int kv0 = td << 6;
    u16* dK = sK + (td & 1) * (64 * 128);
    u16* dV = sV + (td & 1) * (128 * 64);
    #pragma unroll
    for (int c = 0; c < 4; c++) {
      int rk = c * 16 + wave * 4 + k_r_sub;
      int kgl = (lane & 15) ^ (rk & 7);
      async_cp16(&Kg[(size_t)(kv0 + rk) * HD + kgl * 8], &dK[(c * 256 + wave * 64) * 8]);
      int rv = c * 32 + wave * 8 + v_r_sub;
      async_cp16(&Vg[(size_t)rv * T_SEQ + kv0 + v_gl * 8], &dV[(c * 256 + wave * 64) * 8]);
    }
  };

  stage(0);
  if (nt > 1) stage(1);

  for (int ti = 0; ti < nt; ++ti) {
    if (ti + 1 < nt) { asm volatile("s_waitcnt vmcnt(8)" ::: "memory"); }
    else             { asm volatile("s_waitcnt vmcnt(0)" ::: "memory"); }
    __builtin_amdgcn_s_barrier();   // publish tile ti

    const u16* cK = sK + (ti & 1) * (64 * 128);
    const u16* cV = sV + (ti & 1) * (128 * 64);
    const int kv0 = ti << 6;

    // S = Q Ktile^T : rows quad*4+r (q), col lm (kv within 16-tile)
    f32x4 s[4];
    __builtin_amdgcn_s_setprio(1);
    #pragma unroll
    for (int nt4 = 0; nt4 < 4; nt4++) {
      s[nt4] = fzero;
      #pragma unroll
      for (int kb = 0; kb < 4; kb++) {
        int row = nt4 * 16 + lm;
        bf16x8 bk = *(const bf16x8*)&cK[row * 128 + (((kb * 4 + quad) ^ (lm & 7)) * 8)];
        s[nt4] = __builtin_amdgcn_mfma_f32_16x16x32_bf16(aq[kb], bk, s[nt4], 0, 0, 0);
      }
    }
    __builtin_amdgcn_s_setprio(0);

    // fixed-shift softmax numerator; per-lane partial l; no cross-lane ops
    #pragma unroll
    for (int r = 0; r < 4; r++) {
      int qr = q0 + wave * 16 + quad * 4 + r;
      #pragma unroll
      for (int nt4 = 0; nt4 < 4; nt4++) {
        int kvc = kv0 + nt4 * 16 + lm;
        float p = exp2f(fmaf(s[nt4][r], C1, C2));
        p = (kvc > qr) ? 0.f : p;
        l4[r] += p;
        sPw[(quad * 4 + r) * 72 + nt4 * 16 + lm] = f2bf(p);
      }
    }
    // no barrier: sPw is wave-private; lgkmcnt orders ds_write -> ds_read.

    // O += P * Vtile  (P via LDS: C-layout -> A-layout)
    __builtin_amdgcn_s_setprio(1);
    #pragma unroll
    for (int kb2 = 0; kb2 < 2; kb2++) {
      bf16x8 ap = *(const bf16x8*)&sPw[lm * 72 + kb2 * 32 + quad * 8];
      #pragma unroll
      for (int n8 = 0; n8 < 8; n8++) {
        int row = n8 * 16 + lm;
        bf16x8 bv = *(const bf16x8*)&cV[row * 64 + (((kb2 * 4 + quad) ^ (lm & 7)) * 8)];
        o[n8] = __builtin_amdgcn_mfma_f32_16x16x32_bf16(ap, bv, o[n8], 0, 0, 0);
      }
    }
    __builtin_amdgcn_s_setprio(0);

    __builtin_amdgcn_s_barrier();   // retire buf (ti&1): all waves done reading
    if (ti + 2 < nt) stage(ti + 2); // overwrite buf (ti&1) for tile ti+2
  }

  // one-time l reduction across the 16 lm-lanes (xor offsets stay in-quad)
  #pragma unroll
  for (int r = 0; r < 4; r++) {
    #pragma unroll
    for (int off = 1; off < 16; off <<= 1) l4[r] += __shfl_xor(l4[r], off, 64);
  }

  #pragma unroll
  for (int r = 0; r < 4; r++) {
    float inv = 1.f / l4[r];
    #pragma unroll
    for (int n8 = 0; n8 < 8; n8++) {
      ctx[(size_t)(q0 + wave * 16 + quad * 4 + r) * D_MODEL + h * HD + n8 * 16 + lm]
          = f2bf(o[n8][r] * inv);
    }
  }
}

extern "C" void kernel_launch(void* const* d_in, const int* in_sizes, int n_in,
                              void* d_out, int out_size, void* d_ws, size_t ws_size,
                              hipStream_t stream)
{
  const float* x   = (const float*)d_in[0];
  const float* Wq  = (const float*)d_in[1];
  const float* Wkv = (const float*)d_in[2];
  const float* Wo  = (const float*)d_in[3];
  const float* bo  = (const float*)d_in[4];
  float* out = (float*)d_out;

  char* ws = (char*)d_ws;
  const size_t SZ_T   = 33554432;  // 4096*4096*2 (bf16)
  const size_t SZ_ACT = 16777216;  // 2048*4096*2 (bf16)
  const size_t SZ_KV  = 4194304;   // 8*2048*128*2 (bf16)
  u16* Tb = (u16*)(ws);
  u16* Xb = (u16*)(ws + SZ_T);
  u16* Qb = (u16*)(ws + SZ_T + SZ_ACT);
  u16* Cx = (u16*)(ws + SZ_T + 2 * SZ_ACT);
  u16* Kb = (u16*)(ws + SZ_T + 3 * SZ_ACT);
  u16* Vb = (u16*)(ws + SZ_T + 3 * SZ_ACT + SZ_KV);
  u16* Vt = (u16*)(ws + SZ_T + 3 * SZ_ACT + 2 * SZ_KV);

  // 0. x -> bf16
  cvt_k<<<dim3(8192, 1, 1), 256, 0, stream>>>(x, Xb, 2097152);
  // 1. Q = x @ Wq           (Wq^T staged into Tb, fp32->bf16)
  transpose_k<float><<<dim3(128, 128, 1), 256, 0, stream>>>(Wq, Tb, 4096, 4096);
  gemm_k<0><<<dim3(32, 16, 1), 256, 0, stream>>>(Xb, Tb, Qb, nullptr, nullptr, nullptr, nullptr, 4096, 4096);
  // 2. K,V = split(x @ Wkv)
  transpose_k<float><<<dim3(64, 128, 1), 256, 0, stream>>>(Wkv, Tb, 4096, 2048);
  gemm_k<1><<<dim3(16, 16, 1), 256, 0, stream>>>(Xb, Tb, nullptr, Kb, Vb, nullptr, nullptr, 4096, 2048);
  // 3. V^T per group: [g][t][hd] -> [g][hd][t]  (bf16 -> bf16)
  transpose_k<u16><<<dim3(4, 64, 8), 256, 0, stream>>>(Vb, Vt, 2048, 128);
  // 4. flash attention -> ctx (bf16)
  attn_k<<<dim3(32, 32, 1), 256, 0, stream>>>(Qb, Kb, Vt, Cx);
  // 5. out = ctx @ Wo + bo  (fp32 out, fp32 bias)
  transpose_k<float><<<dim3(128, 128, 1), 256, 0, stream>>>(Wo, Tb, 4096, 4096);
  gemm_k<2><<<dim3(32, 16, 1), 256, 0, stream>>>(Cx, Tb, nullptr, nullptr, nullptr, out, bo, 4096, 4096);
}

// Round 4
// 488.777 us; speedup vs baseline: 1.5092x; 1.0561x over previous
//
#include <hip/hip_runtime.h>

#define T_SEQ 2048
#define D_MODEL 4096
#define NH 32
#define NG 8
#define HD 128

typedef unsigned short u16;
typedef __bf16 bf16x8 __attribute__((ext_vector_type(8)));
typedef float f32x4 __attribute__((ext_vector_type(4)));

#define AS1 __attribute__((address_space(1)))
#define AS3 __attribute__((address_space(3)))

__device__ __forceinline__ void async_cp16(const u16* g, u16* l) {
  // global -> LDS direct copy, 16B per lane. LDS dest is wave-uniform base + lane*16.
  __builtin_amdgcn_global_load_lds((AS1 void*)g, (AS3 void*)l, 16, 0, 0);
}

__device__ __forceinline__ u16 f2bf(float f){
  union { float f; unsigned x; } v; v.f = f;
  unsigned r = v.x + 0x7FFFu + ((v.x >> 16) & 1u);
  return (u16)(r >> 16);
}
__device__ __forceinline__ u16 to_bf(float f){ return f2bf(f); }
__device__ __forceinline__ u16 to_bf(u16 u){ return u; }

// ---------------- convert fp32 -> bf16, vectorized ----------------
__global__ __launch_bounds__(256) void cvt_k(const float* __restrict__ in,
                                             u16* __restrict__ out, int n4)
{
  int i = blockIdx.x * 256 + threadIdx.x;
  if (i >= n4) return;
  float4 v = *(const float4*)&in[(size_t)i * 4];
  short4 o;
  o.x = (short)f2bf(v.x); o.y = (short)f2bf(v.y);
  o.z = (short)f2bf(v.z); o.w = (short)f2bf(v.w);
  *(short4*)&out[(size_t)i * 4] = o;
}

// ---------------- transpose + cvt: out[c][r] = bf16(in[r][c]) ----------------
template<typename TIN>
__global__ __launch_bounds__(256) void transpose_k(const TIN* __restrict__ in,
                                                   u16* __restrict__ out, int R, int C)
{
  int z = blockIdx.z;
  in  += (size_t)z * R * C;
  out += (size_t)z * R * C;
  __shared__ __align__(16) u16 tile[32][36];
  int c0 = blockIdx.x * 32, r0 = blockIdx.y * 32;
  int t = threadIdx.x;
  int lr = t >> 3, lc = (t & 7) * 4;
  const TIN* src = &in[(size_t)(r0 + lr) * C + c0 + lc];
  #pragma unroll
  for (int i = 0; i < 4; i++) tile[lr][lc + i] = to_bf(src[i]);
  __syncthreads();
  short4 v;
  v.x = (short)tile[lc + 0][lr];
  v.y = (short)tile[lc + 1][lr];
  v.z = (short)tile[lc + 2][lr];
  v.w = (short)tile[lc + 3][lr];
  *(short4*)&out[(size_t)(c0 + lr) * R + r0 + lc] = v;
}

// ---------------- GEMM: C[M x N] = A[M x K] * BT[N x K]^T, bf16 in, fp32 acc ------
// Double-buffered LDS (64 KB) + raw s_barrier + counted vmcnt(8): stage(t+2)
// issues after the retire barrier; loop top waits vmcnt(8) (one stage = 8
// gload_lds per thread in flight) instead of draining to 0 -- staging latency
// hides under a full K-step of MFMA.  Same pattern that took attn 149.7->~90us.
// LDS tiles [128 rows][64 k] unpadded, 16B-group XOR swizzle: phys_g = g ^ (row&7).
// MODE 0: store bf16 to Cout
// MODE 1: KV scatter: col -> (g,s,hd); K to Kout[g][t][hd], V DIRECTLY to
//         Vt[g][hd][t] (fused transpose, packed 8B stores over 4 consecutive t)
// MODE 2: store fp32 to Fout with fp32 bias add
template<int MODE>
__global__ __launch_bounds__(256) void gemm_k(
    const u16* __restrict__ A, const u16* __restrict__ BT,
    u16* __restrict__ Cout, u16* __restrict__ Kout, u16* __restrict__ Vout,
    float* __restrict__ Fout, const float* __restrict__ bias, int K, int N)
{
  __shared__ __align__(16) u16 sA[2 * 128 * 64];
  __shared__ __align__(16) u16 sB[2 * 128 * 64];
  const int t = threadIdx.x;
  const int lane = t & 63, wave = t >> 6;
  const int quad = lane >> 4, lm = lane & 15;
  const int wm = wave >> 1, wn = wave & 1;
  const int m0 = blockIdx.y * 128, n0 = blockIdx.x * 128;
  const int ntk = K >> 6;
  const f32x4 fzero = {0.f, 0.f, 0.f, 0.f};

  const int sr_sub = lane >> 3;            // 0..7
  const int sgl = (lane & 7) ^ sr_sub;     // swizzled logical 16B group

  f32x4 acc[4][4];
  #pragma unroll
  for (int i = 0; i < 4; i++)
    #pragma unroll
    for (int j = 0; j < 4; j++) acc[i][j] = fzero;

  auto stage = [&](int td) {
    const int k0 = td << 6;
    u16* dA = sA + (td & 1) * (128 * 64);
    u16* dB = sB + (td & 1) * (128 * 64);
    #pragma unroll
    for (int c = 0; c < 4; c++) {
      int r = c * 32 + wave * 8 + sr_sub;
      async_cp16(&A [(size_t)(m0 + r) * K + k0 + sgl * 8], &dA[(c * 256 + wave * 64) * 8]);
      async_cp16(&BT[(size_t)(n0 + r) * K + k0 + sgl * 8], &dB[(c * 256 + wave * 64) * 8]);
    }
  };

  stage(0);
  stage(1);

  for (int ti = 0; ti < ntk; ++ti) {
    if (ti + 1 < ntk) { asm volatile("s_waitcnt vmcnt(8)" ::: "memory"); }
    else             { asm volatile("s_waitcnt vmcnt(0)" ::: "memory"); }
    __builtin_amdgcn_s_barrier();   // publish tile ti
    asm volatile("" ::: "memory");

    const u16* cA = sA + (ti & 1) * (128 * 64);
    const u16* cB = sB + (ti & 1) * (128 * 64);

    __builtin_amdgcn_s_setprio(1);
    #pragma unroll
    for (int kb = 0; kb < 2; kb++) {
      bf16x8 af[4], bfr[4];
      #pragma unroll
      for (int mt = 0; mt < 4; mt++) {
        int row = wm * 64 + mt * 16 + lm;
        af[mt] = *(const bf16x8*)&cA[row * 64 + (((kb * 4 + quad) ^ (lm & 7)) * 8)];
      }
      #pragma unroll
      for (int nt = 0; nt < 4; nt++) {
        int row = wn * 64 + nt * 16 + lm;
        bfr[nt] = *(const bf16x8*)&cB[row * 64 + (((kb * 4 + quad) ^ (lm & 7)) * 8)];
      }
      #pragma unroll
      for (int mt = 0; mt < 4; mt++)
        #pragma unroll
        for (int nt = 0; nt < 4; nt++)
          acc[mt][nt] = __builtin_amdgcn_mfma_f32_16x16x32_bf16(af[mt], bfr[nt], acc[mt][nt], 0, 0, 0);
    }
    __builtin_amdgcn_s_setprio(0);

    __builtin_amdgcn_s_barrier();   // retire buf (ti&1)
    asm volatile("" ::: "memory");
    if (ti + 2 < ntk) stage(ti + 2);
  }

  #pragma unroll
  for (int mt = 0; mt < 4; mt++) {
    #pragma unroll
    for (int nt = 0; nt < 4; nt++) {
      int gcol = n0 + wn * 64 + nt * 16 + lm;
      int grow0 = m0 + wm * 64 + mt * 16 + quad * 4;
      if (MODE == 1 && ((gcol >> 7) & 1)) {
        // V half: fused transpose -> Vt[g][hd][t], 4 consecutive t packed in 8B
        int g = gcol >> 8, hd = gcol & 127;
        short4 pv;
        pv.x = (short)f2bf(acc[mt][nt][0]);
        pv.y = (short)f2bf(acc[mt][nt][1]);
        pv.z = (short)f2bf(acc[mt][nt][2]);
        pv.w = (short)f2bf(acc[mt][nt][3]);
        *(short4*)&Vout[((size_t)g * HD + hd) * T_SEQ + grow0] = pv;
      } else {
        #pragma unroll
        for (int r = 0; r < 4; r++) {
          int grow = grow0 + r;
          float v = acc[mt][nt][r];
          if (MODE == 0) {
            Cout[(size_t)grow * N + gcol] = f2bf(v);
          } else if (MODE == 1) {
            int g = gcol >> 8, hd = gcol & 127;
            Kout[((size_t)g * T_SEQ + grow) * HD + hd] = f2bf(v);
          } else {
            Fout[(size_t)grow * N + gcol] = v + bias[gcol];
          }
        }
      }
    }
  }
}

// ---------------- flash attention, double-buffered staging + counted vmcnt ------
// Q[t][h*128], K[g][t][128], Vt[g][128][t] -> ctx[t][h*128]
// sK/sV double-buffered (74.7 KB LDS, 2 blocks/CU); stage(t+2) issues after the
// retire barrier; loop top waits vmcnt(8) (= one tile's 8 gload_lds in flight,
// never 0 except the final tile) so staging latency hides under a full tile of
// QK+softmax+PV compute.  XCD remap: id%8 = KV group pins each group's 1MB K/V
// to one XCD's L2.  Fixed-shift softmax: p = exp2(s*C1+C2), shift-invariant
// ratio, no running max, l reduced once after the loop.
__global__ __launch_bounds__(256) void attn_k(
    const u16* __restrict__ Q, const u16* __restrict__ Kb,
    const u16* __restrict__ Vt, u16* __restrict__ ctx)
{
  __shared__ __align__(16) u16 sK[2 * 64 * 128];
  __shared__ __align__(16) u16 sV[2 * 128 * 64];
  __shared__ __align__(16) u16 sP[4 * 16 * 72];  // per-wave [16 q][64 kv + pad8]
  const int t = threadIdx.x;
  const int lane = t & 63, wave = t >> 6;
  const int quad = lane >> 4, lm = lane & 15;

  // id -> (g, rep, q-block): round-robin %8 pins group g to one XCD
  const int id = blockIdx.x + gridDim.x * blockIdx.y;
  const int g = id & 7;
  const int idx = id >> 3;                       // 0..127
  const int h = g * 4 + (idx & 3);               // REP = 4
  const int q0 = (31 - (idx >> 2)) * 64;         // longest first
  const int nt = (q0 >> 6) + 1;                  // causal kv-tile count

  const float scale = 0.088388347648318447f;     // 1/sqrt(128)
  const float C1 = scale * 1.4426950408889634f;  // to exp2 domain
  const float C2 = -14.0f * 1.4426950408889634f; // fixed shift M0 = 14
  const f32x4 fzero = {0.f, 0.f, 0.f, 0.f};

  bf16x8 aq[4];
  {
    const u16* qp = Q + (size_t)(q0 + wave * 16 + lm) * D_MODEL + h * HD + quad * 8;
    #pragma unroll
    for (int kb = 0; kb < 4; kb++) aq[kb] = *(const bf16x8*)(qp + kb * 32);
  }
  f32x4 o[8];
  #pragma unroll
  for (int i = 0; i < 8; i++) o[i] = fzero;
  float l4[4];
  #pragma unroll
  for (int r = 0; r < 4; r++) l4[r] = 0.f;

  const u16* Kg = Kb + (size_t)g * T_SEQ * HD;
  const u16* Vg = Vt + (size_t)g * HD * T_SEQ;
  u16* sPw = sP + wave * 16 * 72;

  // staging geometry (8 gload_lds per thread per tile: 4 K + 4 V)
  const int k_r_sub = lane >> 4;                    // 0..3 (16 groups/row for sK)
  const int v_r_sub = lane >> 3;                    // 0..7 (8 groups/row for sV)
  const int v_gl = (lane & 7) ^ v_r_sub;

  auto stage = [&](int td) {
    const int kv0 = td << 6;
    u16* dK = sK + (td & 1) * (64 * 128);
    u16* dV = sV + (td & 1) * (128 * 64);
    #pragma unroll
    for (int c = 0; c < 4; c++) {
      int rk = c * 16 + wave * 4 + k_r_sub;
      int kgl = (lane & 15) ^ (rk & 7);
      async_cp16(&Kg[(size_t)(kv0 + rk) * HD + kgl * 8], &dK[(c * 256 + wave * 64) * 8]);
      int rv = c * 32 + wave * 8 + v_r_sub;
      async_cp16(&Vg[(size_t)rv * T_SEQ + kv0 + v_gl * 8], &dV[(c * 256 + wave * 64) * 8]);
    }
  };

  stage(0);
  if (nt > 1) stage(1);

  for (int ti = 0; ti < nt; ++ti) {
    if (ti + 1 < nt) { asm volatile("s_waitcnt vmcnt(8)" ::: "memory"); }
    else             { asm volatile("s_waitcnt vmcnt(0)" ::: "memory"); }
    __builtin_amdgcn_s_barrier();   // publish tile ti
    asm volatile("" ::: "memory");

    const u16* cK = sK + (ti & 1) * (64 * 128);
    const u16* cV = sV + (ti & 1) * (128 * 64);
    const int kv0 = ti << 6;

    // S = Q Ktile^T : rows quad*4+r (q), col lm (kv within 16-tile)
    f32x4 s[4];
    __builtin_amdgcn_s_setprio(1);
    #pragma unroll
    for (int nt4 = 0; nt4 < 4; nt4++) {
      s[nt4] = fzero;
      #pragma unroll
      for (int kb = 0; kb < 4; kb++) {
        int row = nt4 * 16 + lm;
        bf16x8 bk = *(const bf16x8*)&cK[row * 128 + (((kb * 4 + quad) ^ (lm & 7)) * 8)];
        s[nt4] = __builtin_amdgcn_mfma_f32_16x16x32_bf16(aq[kb], bk, s[nt4], 0, 0, 0);
      }
    }
    __builtin_amdgcn_s_setprio(0);

    // fixed-shift softmax numerator; per-lane partial l; no cross-lane ops
    #pragma unroll
    for (int r = 0; r < 4; r++) {
      int qr = q0 + wave * 16 + quad * 4 + r;
      #pragma unroll
      for (int nt4 = 0; nt4 < 4; nt4++) {
        int kvc = kv0 + nt4 * 16 + lm;
        float p = exp2f(fmaf(s[nt4][r], C1, C2));
        p = (kvc > qr) ? 0.f : p;
        l4[r] += p;
        sPw[(quad * 4 + r) * 72 + nt4 * 16 + lm] = f2bf(p);
      }
    }
    // no barrier: sPw is wave-private; lgkmcnt orders ds_write -> ds_read.

    // O += P * Vtile  (P via LDS: C-layout -> A-layout)
    __builtin_amdgcn_s_setprio(1);
    #pragma unroll
    for (int kb2 = 0; kb2 < 2; kb2++) {
      bf16x8 ap = *(const bf16x8*)&sPw[lm * 72 + kb2 * 32 + quad * 8];
      #pragma unroll
      for (int n8 = 0; n8 < 8; n8++) {
        int row = n8 * 16 + lm;
        bf16x8 bv = *(const bf16x8*)&cV[row * 64 + (((kb2 * 4 + quad) ^ (lm & 7)) * 8)];
        o[n8] = __builtin_amdgcn_mfma_f32_16x16x32_bf16(ap, bv, o[n8], 0, 0, 0);
      }
    }
    __builtin_amdgcn_s_setprio(0);

    __builtin_amdgcn_s_barrier();   // retire buf (ti&1): all waves done reading
    asm volatile("" ::: "memory");
    if (ti + 2 < nt) stage(ti + 2); // overwrite buf (ti&1) for tile ti+2
  }

  // one-time l reduction across the 16 lm-lanes (xor offsets stay in-quad)
  #pragma unroll
  for (int r = 0; r < 4; r++) {
    #pragma unroll
    for (int off = 1; off < 16; off <<= 1) l4[r] += __shfl_xor(l4[r], off, 64);
  }

  #pragma unroll
  for (int r = 0; r < 4; r++) {
    float inv = 1.f / l4[r];
    #pragma unroll
    for (int n8 = 0; n8 < 8; n8++) {
      ctx[(size_t)(q0 + wave * 16 + quad * 4 + r) * D_MODEL + h * HD + n8 * 16 + lm]
          = f2bf(o[n8][r] * inv);
    }
  }
}

extern "C" void kernel_launch(void* const* d_in, const int* in_sizes, int n_in,
                              void* d_out, int out_size, void* d_ws, size_t ws_size,
                              hipStream_t stream)
{
  const float* x   = (const float*)d_in[0];
  const float* Wq  = (const float*)d_in[1];
  const float* Wkv = (const float*)d_in[2];
  const float* Wo  = (const float*)d_in[3];
  const float* bo  = (const float*)d_in[4];
  float* out = (float*)d_out;

  char* ws = (char*)d_ws;
  const size_t SZ_T   = 33554432;  // 4096*4096*2 (bf16)
  const size_t SZ_ACT = 16777216;  // 2048*4096*2 (bf16)
  const size_t SZ_KV  = 4194304;   // 8*2048*128*2 (bf16)
  u16* Tb = (u16*)(ws);
  u16* Xb = (u16*)(ws + SZ_T);
  u16* Qb = (u16*)(ws + SZ_T + SZ_ACT);
  u16* Cx = (u16*)(ws + SZ_T + 2 * SZ_ACT);
  u16* Kb = (u16*)(ws + SZ_T + 3 * SZ_ACT);
  u16* Vt = (u16*)(ws + SZ_T + 3 * SZ_ACT + SZ_KV);

  // 0. x -> bf16
  cvt_k<<<dim3(8192, 1, 1), 256, 0, stream>>>(x, Xb, 2097152);
  // 1. Q = x @ Wq           (Wq^T staged into Tb, fp32->bf16)
  transpose_k<float><<<dim3(128, 128, 1), 256, 0, stream>>>(Wq, Tb, 4096, 4096);
  gemm_k<0><<<dim3(32, 16, 1), 256, 0, stream>>>(Xb, Tb, Qb, nullptr, nullptr, nullptr, nullptr, 4096, 4096);
  // 2. K,V = split(x @ Wkv); V transposed in-epilogue -> Vt[g][hd][t]
  transpose_k<float><<<dim3(64, 128, 1), 256, 0, stream>>>(Wkv, Tb, 4096, 2048);
  gemm_k<1><<<dim3(16, 16, 1), 256, 0, stream>>>(Xb, Tb, nullptr, Kb, Vt, nullptr, nullptr, 4096, 2048);
  // 3. flash attention -> ctx (bf16)
  attn_k<<<dim3(32, 32, 1), 256, 0, stream>>>(Qb, Kb, Vt, Cx);
  // 4. out = ctx @ Wo + bo  (fp32 out, fp32 bias)
  transpose_k<float><<<dim3(128, 128, 1), 256, 0, stream>>>(Wo, Tb, 4096, 4096);
  gemm_k<2><<<dim3(32, 16, 1), 256, 0, stream>>>(Cx, Tb, nullptr, nullptr, nullptr, out, bo, 4096, 4096);
}

// Round 6
// 473.159 us; speedup vs baseline: 1.5590x; 1.0330x over previous
//
#include <hip/hip_runtime.h>

#define T_SEQ 2048
#define D_MODEL 4096
#define NH 32
#define NG 8
#define HD 128

typedef unsigned short u16;
typedef __bf16 bf16x8 __attribute__((ext_vector_type(8)));
typedef float f32x4 __attribute__((ext_vector_type(4)));

#define AS1 __attribute__((address_space(1)))
#define AS3 __attribute__((address_space(3)))

__device__ __forceinline__ void async_cp16(const u16* g, u16* l) {
  // global -> LDS direct copy, 16B per lane. LDS dest is wave-uniform base + lane*16.
  __builtin_amdgcn_global_load_lds((AS1 void*)g, (AS3 void*)l, 16, 0, 0);
}

__device__ __forceinline__ u16 f2bf(float f){
  union { float f; unsigned x; } v; v.f = f;
  unsigned r = v.x + 0x7FFFu + ((v.x >> 16) & 1u);
  return (u16)(r >> 16);
}
__device__ __forceinline__ u16 to_bf(float f){ return f2bf(f); }
__device__ __forceinline__ u16 to_bf(u16 u){ return u; }

// ---------------- convert fp32 -> bf16, vectorized ----------------
__global__ __launch_bounds__(256) void cvt_k(const float* __restrict__ in,
                                             u16* __restrict__ out, int n4)
{
  int i = blockIdx.x * 256 + threadIdx.x;
  if (i >= n4) return;
  float4 v = *(const float4*)&in[(size_t)i * 4];
  short4 o;
  o.x = (short)f2bf(v.x); o.y = (short)f2bf(v.y);
  o.z = (short)f2bf(v.z); o.w = (short)f2bf(v.w);
  *(short4*)&out[(size_t)i * 4] = o;
}

// ---------------- transpose + cvt: out[c][r] = bf16(in[r][c]) ----------------
template<typename TIN>
__global__ __launch_bounds__(256) void transpose_k(const TIN* __restrict__ in,
                                                   u16* __restrict__ out, int R, int C)
{
  __shared__ __align__(16) u16 tile[32][36];
  int c0 = blockIdx.x * 32, r0 = blockIdx.y * 32;
  int t = threadIdx.x;
  int lr = t >> 3, lc = (t & 7) * 4;
  const TIN* src = &in[(size_t)(r0 + lr) * C + c0 + lc];
  #pragma unroll
  for (int i = 0; i < 4; i++) tile[lr][lc + i] = to_bf(src[i]);
  __syncthreads();
  short4 v;
  v.x = (short)tile[lc + 0][lr];
  v.y = (short)tile[lc + 1][lr];
  v.z = (short)tile[lc + 2][lr];
  v.w = (short)tile[lc + 3][lr];
  *(short4*)&out[(size_t)(c0 + lr) * R + r0 + lc] = v;
}

// ---------------- GEMM: C[M x N] = A[M x K] * BT[N x K]^T, bf16 in, fp32 acc ------
// Double-buffered LDS (64 KB) + raw s_barrier + counted vmcnt(8): stage(t+2)
// issues after the retire barrier; loop top waits vmcnt(8) (one stage = 8
// gload_lds per thread in flight) instead of draining to 0 -- staging latency
// hides under a full K-step of MFMA.
// LDS tiles [128 rows][64 k] unpadded, 16B-group XOR swizzle: phys_g = g ^ (row&7).
// MODE 1: fused QKV projection over N=6144 ([Wq|Wkv]^T staged contiguously):
//         col < 4096 -> Q[t][4096] (bf16); col >= 4096 -> (g,s,hd) scatter,
//         K to Kout[g][t][hd], V DIRECTLY to Vt[g][hd][t] (fused transpose,
//         packed 8B stores over 4 consecutive t).
// MODE 2: store fp32 to Fout with fp32 bias add
template<int MODE>
__global__ __launch_bounds__(256) void gemm_k(
    const u16* __restrict__ A, const u16* __restrict__ BT,
    u16* __restrict__ Cout, u16* __restrict__ Kout, u16* __restrict__ Vout,
    float* __restrict__ Fout, const float* __restrict__ bias, int K, int N)
{
  __shared__ __align__(16) u16 sA[2 * 128 * 64];
  __shared__ __align__(16) u16 sB[2 * 128 * 64];
  const int t = threadIdx.x;
  const int lane = t & 63, wave = t >> 6;
  const int quad = lane >> 4, lm = lane & 15;
  const int wm = wave >> 1, wn = wave & 1;
  const int m0 = blockIdx.y * 128, n0 = blockIdx.x * 128;
  const int ntk = K >> 6;
  const f32x4 fzero = {0.f, 0.f, 0.f, 0.f};

  const int sr_sub = lane >> 3;            // 0..7
  const int sgl = (lane & 7) ^ sr_sub;     // swizzled logical 16B group

  f32x4 acc[4][4];
  #pragma unroll
  for (int i = 0; i < 4; i++)
    #pragma unroll
    for (int j = 0; j < 4; j++) acc[i][j] = fzero;

  auto stage = [&](int td) {
    const int k0 = td << 6;
    u16* dA = sA + (td & 1) * (128 * 64);
    u16* dB = sB + (td & 1) * (128 * 64);
    #pragma unroll
    for (int c = 0; c < 4; c++) {
      int r = c * 32 + wave * 8 + sr_sub;
      async_cp16(&A [(size_t)(m0 + r) * K + k0 + sgl * 8], &dA[(c * 256 + wave * 64) * 8]);
      async_cp16(&BT[(size_t)(n0 + r) * K + k0 + sgl * 8], &dB[(c * 256 + wave * 64) * 8]);
    }
  };

  stage(0);
  stage(1);

  for (int ti = 0; ti < ntk; ++ti) {
    if (ti + 1 < ntk) { asm volatile("s_waitcnt vmcnt(8)" ::: "memory"); }
    else             { asm volatile("s_waitcnt vmcnt(0)" ::: "memory"); }
    __builtin_amdgcn_s_barrier();   // publish tile ti
    asm volatile("" ::: "memory");

    const u16* cA = sA + (ti & 1) * (128 * 64);
    const u16* cB = sB + (ti & 1) * (128 * 64);

    __builtin_amdgcn_s_setprio(1);
    #pragma unroll
    for (int kb = 0; kb < 2; kb++) {
      bf16x8 af[4], bfr[4];
      #pragma unroll
      for (int mt = 0; mt < 4; mt++) {
        int row = wm * 64 + mt * 16 + lm;
        af[mt] = *(const bf16x8*)&cA[row * 64 + (((kb * 4 + quad) ^ (lm & 7)) * 8)];
      }
      #pragma unroll
      for (int nt = 0; nt < 4; nt++) {
        int row = wn * 64 + nt * 16 + lm;
        bfr[nt] = *(const bf16x8*)&cB[row * 64 + (((kb * 4 + quad) ^ (lm & 7)) * 8)];
      }
      #pragma unroll
      for (int mt = 0; mt < 4; mt++)
        #pragma unroll
        for (int nt = 0; nt < 4; nt++)
          acc[mt][nt] = __builtin_amdgcn_mfma_f32_16x16x32_bf16(af[mt], bfr[nt], acc[mt][nt], 0, 0, 0);
    }
    __builtin_amdgcn_s_setprio(0);

    __builtin_amdgcn_s_barrier();   // retire buf (ti&1)
    asm volatile("" ::: "memory");
    if (ti + 2 < ntk) stage(ti + 2);
  }

  #pragma unroll
  for (int mt = 0; mt < 4; mt++) {
    #pragma unroll
    for (int nt = 0; nt < 4; nt++) {
      int gcol = n0 + wn * 64 + nt * 16 + lm;
      int grow0 = m0 + wm * 64 + mt * 16 + quad * 4;
      if (MODE == 1) {
        if (gcol < 4096) {
          #pragma unroll
          for (int r = 0; r < 4; r++)
            Cout[(size_t)(grow0 + r) * 4096 + gcol] = f2bf(acc[mt][nt][r]);
        } else {
          int c = gcol - 4096;
          int g = c >> 8, s = (c >> 7) & 1, hd = c & 127;
          if (s) {
            // V half: fused transpose -> Vt[g][hd][t], 4 consecutive t in 8B
            short4 pv;
            pv.x = (short)f2bf(acc[mt][nt][0]);
            pv.y = (short)f2bf(acc[mt][nt][1]);
            pv.z = (short)f2bf(acc[mt][nt][2]);
            pv.w = (short)f2bf(acc[mt][nt][3]);
            *(short4*)&Vout[((size_t)g * HD + hd) * T_SEQ + grow0] = pv;
          } else {
            #pragma unroll
            for (int r = 0; r < 4; r++)
              Kout[((size_t)g * T_SEQ + grow0 + r) * HD + hd] = f2bf(acc[mt][nt][r]);
          }
        }
      } else {
        #pragma unroll
        for (int r = 0; r < 4; r++)
          Fout[(size_t)(grow0 + r) * N + gcol] = acc[mt][nt][r] + bias[gcol];
      }
    }
  }
}

// ---------------- flash attention, double-buffered staging + counted vmcnt ------
// Q[t][h*128], K[g][t][128], Vt[g][128][t] -> ctx[t][h*128]
// sK/sV double-buffered (74.7 KB LDS, 2 blocks/CU); stage(t+2) after the retire
// barrier; loop top waits vmcnt(8) (never 0 except final tile).
// VALU diet vs r4: (a) causal mask applied ONLY on the diagonal tile (for
// ti < nt-1, max kvc = kv0+63 <= q0-1 < qr always); (b) l computed by MFMA
// against an all-ones B fragment (row-sum lands replicated across lanes in the
// accumulator -> no per-lane adds, no epilogue shuffle reduce).
// XCD remap: id%8 = KV group pins each group's 1MB K/V to one XCD's L2.
// Fixed-shift softmax: p = exp2(s*C1+C2), shift-invariant ratio.
__global__ __launch_bounds__(256) void attn_k(
    const u16* __restrict__ Q, const u16* __restrict__ Kb,
    const u16* __restrict__ Vt, u16* __restrict__ ctx)
{
  __shared__ __align__(16) u16 sK[2 * 64 * 128];
  __shared__ __align__(16) u16 sV[2 * 128 * 64];
  __shared__ __align__(16) u16 sP[4 * 16 * 72];  // per-wave [16 q][64 kv + pad8]
  const int t = threadIdx.x;
  const int lane = t & 63, wave = t >> 6;
  const int quad = lane >> 4, lm = lane & 15;

  // id -> (g, rep, q-block): round-robin %8 pins group g to one XCD
  const int id = blockIdx.x + gridDim.x * blockIdx.y;
  const int g = id & 7;
  const int idx = id >> 3;                       // 0..127
  const int h = g * 4 + (idx & 3);               // REP = 4
  const int q0 = (31 - (idx >> 2)) * 64;         // longest first
  const int nt = (q0 >> 6) + 1;                  // causal kv-tile count

  const float scale = 0.088388347648318447f;     // 1/sqrt(128)
  const float C1 = scale * 1.4426950408889634f;  // to exp2 domain
  const float C2 = -14.0f * 1.4426950408889634f; // fixed shift M0 = 14
  const f32x4 fzero = {0.f, 0.f, 0.f, 0.f};

  bf16x8 aq[4];
  {
    const u16* qp = Q + (size_t)(q0 + wave * 16 + lm) * D_MODEL + h * HD + quad * 8;
    #pragma unroll
    for (int kb = 0; kb < 4; kb++) aq[kb] = *(const bf16x8*)(qp + kb * 32);
  }
  bf16x8 bones;
  #pragma unroll
  for (int i = 0; i < 8; i++) bones[i] = (__bf16)1.0f;

  f32x4 o[8];
  #pragma unroll
  for (int i = 0; i < 8; i++) o[i] = fzero;
  f32x4 lacc = fzero;

  const u16* Kg = Kb + (size_t)g * T_SEQ * HD;
  const u16* Vg = Vt + (size_t)g * HD * T_SEQ;
  u16* sPw = sP + wave * 16 * 72;

  // staging geometry (8 gload_lds per thread per tile: 4 K + 4 V)
  const int k_r_sub = lane >> 4;                    // 0..3 (16 groups/row for sK)
  const int v_r_sub = lane >> 3;                    // 0..7 (8 groups/row for sV)
  const int v_gl = (lane & 7) ^ v_r_sub;

  auto stage = [&](int td) {
    const int kv0 = td << 6;
    u16* dK = sK + (td & 1) * (64 * 128);
    u16* dV = sV + (td & 1) * (128 * 64);
    #pragma unroll
    for (int c = 0; c < 4; c++) {
      int rk = c * 16 + wave * 4 + k_r_sub;
      int kgl = (lane & 15) ^ (rk & 7);
      async_cp16(&Kg[(size_t)(kv0 + rk) * HD + kgl * 8], &dK[(c * 256 + wave * 64) * 8]);
      int rv = c * 32 + wave * 8 + v_r_sub;
      async_cp16(&Vg[(size_t)rv * T_SEQ + kv0 + v_gl * 8], &dV[(c * 256 + wave * 64) * 8]);
    }
  };

  stage(0);
  if (nt > 1) stage(1);

  for (int ti = 0; ti < nt; ++ti) {
    if (ti + 1 < nt) { asm volatile("s_waitcnt vmcnt(8)" ::: "memory"); }
    else             { asm volatile("s_waitcnt vmcnt(0)" ::: "memory"); }
    __builtin_amdgcn_s_barrier();   // publish tile ti
    asm volatile("" ::: "memory");

    const u16* cK = sK + (ti & 1) * (64 * 128);
    const u16* cV = sV + (ti & 1) * (128 * 64);
    const int kv0 = ti << 6;

    // S = Q Ktile^T : rows quad*4+r (q), col lm (kv within 16-tile)
    f32x4 s[4];
    __builtin_amdgcn_s_setprio(1);
    #pragma unroll
    for (int nt4 = 0; nt4 < 4; nt4++) {
      s[nt4] = fzero;
      #pragma unroll
      for (int kb = 0; kb < 4; kb++) {
        int row = nt4 * 16 + lm;
        bf16x8 bk = *(const bf16x8*)&cK[row * 128 + (((kb * 4 + quad) ^ (lm & 7)) * 8)];
        s[nt4] = __builtin_amdgcn_mfma_f32_16x16x32_bf16(aq[kb], bk, s[nt4], 0, 0, 0);
      }
    }
    __builtin_amdgcn_s_setprio(0);

    // fixed-shift softmax numerator -> sP (bf16); mask only on diagonal tile
    if (ti == nt - 1) {
      #pragma unroll
      for (int r = 0; r < 4; r++) {
        int qr = q0 + wave * 16 + quad * 4 + r;
        #pragma unroll
        for (int nt4 = 0; nt4 < 4; nt4++) {
          int kvc = kv0 + nt4 * 16 + lm;
          float p = exp2f(fmaf(s[nt4][r], C1, C2));
          p = (kvc > qr) ? 0.f : p;
          sPw[(quad * 4 + r) * 72 + nt4 * 16 + lm] = f2bf(p);
        }
      }
    } else {
      #pragma unroll
      for (int r = 0; r < 4; r++) {
        #pragma unroll
        for (int nt4 = 0; nt4 < 4; nt4++) {
          float p = exp2f(fmaf(s[nt4][r], C1, C2));
          sPw[(quad * 4 + r) * 72 + nt4 * 16 + lm] = f2bf(p);
        }
      }
    }
    // no barrier: sPw is wave-private; lgkmcnt orders ds_write -> ds_read.

    // O += P * Vtile ; l += P * ones   (P via LDS: C-layout -> A-layout)
    __builtin_amdgcn_s_setprio(1);
    #pragma unroll
    for (int kb2 = 0; kb2 < 2; kb2++) {
      bf16x8 ap = *(const bf16x8*)&sPw[lm * 72 + kb2 * 32 + quad * 8];
      lacc = __builtin_amdgcn_mfma_f32_16x16x32_bf16(ap, bones, lacc, 0, 0, 0);
      #pragma unroll
      for (int n8 = 0; n8 < 8; n8++) {
        int row = n8 * 16 + lm;
        bf16x8 bv = *(const bf16x8*)&cV[row * 64 + (((kb2 * 4 + quad) ^ (lm & 7)) * 8)];
        o[n8] = __builtin_amdgcn_mfma_f32_16x16x32_bf16(ap, bv, o[n8], 0, 0, 0);
      }
    }
    __builtin_amdgcn_s_setprio(0);

    __builtin_amdgcn_s_barrier();   // retire buf (ti&1): all waves done reading
    asm volatile("" ::: "memory");
    if (ti + 2 < nt) stage(ti + 2); // overwrite buf (ti&1) for tile ti+2
  }

  #pragma unroll
  for (int r = 0; r < 4; r++) {
    float inv = 1.f / lacc[r];     // row-sum replicated across all lanes
    #pragma unroll
    for (int n8 = 0; n8 < 8; n8++) {
      ctx[(size_t)(q0 + wave * 16 + quad * 4 + r) * D_MODEL + h * HD + n8 * 16 + lm]
          = f2bf(o[n8][r] * inv);
    }
  }
}

extern "C" void kernel_launch(void* const* d_in, const int* in_sizes, int n_in,
                              void* d_out, int out_size, void* d_ws, size_t ws_size,
                              hipStream_t stream)
{
  const float* x   = (const float*)d_in[0];
  const float* Wq  = (const float*)d_in[1];
  const float* Wkv = (const float*)d_in[2];
  const float* Wo  = (const float*)d_in[3];
  const float* bo  = (const float*)d_in[4];
  float* out = (float*)d_out;

  char* ws = (char*)d_ws;
  const size_t SZ_T   = 50331648;  // 6144*4096*2 (bf16)  [Wq^T | Wkv^T]
  const size_t SZ_ACT = 16777216;  // 2048*4096*2 (bf16)
  const size_t SZ_KV  = 4194304;   // 8*2048*128*2 (bf16)
  u16* Tb = (u16*)(ws);
  u16* Xb = (u16*)(ws + SZ_T);
  u16* Qb = (u16*)(ws + SZ_T + SZ_ACT);
  u16* Kb = (u16*)(ws + SZ_T + 2 * SZ_ACT);
  u16* Vt = (u16*)(ws + SZ_T + 2 * SZ_ACT + SZ_KV);
  u16* Cx = Xb;  // alias: Xb dead after the fused QKV projection

  // 0. x -> bf16
  cvt_k<<<dim3(8192, 1, 1), 256, 0, stream>>>(x, Xb, 2097152);
  // 1. stage [Wq | Wkv]^T into Tb (fp32 -> bf16)
  transpose_k<float><<<dim3(128, 128, 1), 256, 0, stream>>>(Wq, Tb, 4096, 4096);
  transpose_k<float><<<dim3(64, 128, 1), 256, 0, stream>>>(Wkv, Tb + (size_t)4096 * 4096, 4096, 2048);
  // 2. fused projection: [Q | K | V] = x @ [Wq | Wkv]; V transposed in-epilogue
  gemm_k<1><<<dim3(48, 16, 1), 256, 0, stream>>>(Xb, Tb, Qb, Kb, Vt, nullptr, nullptr, 4096, 6144);
  // 3. flash attention -> ctx (bf16)
  attn_k<<<dim3(32, 32, 1), 256, 0, stream>>>(Qb, Kb, Vt, Cx);
  // 4. out = ctx @ Wo + bo  (fp32 out, fp32 bias)
  transpose_k<float><<<dim3(128, 128, 1), 256, 0, stream>>>(Wo, Tb, 4096, 4096);
  gemm_k<2><<<dim3(32, 16, 1), 256, 0, stream>>>(Cx, Tb, nullptr, nullptr, nullptr, out, bo, 4096, 4096);
}